// Round 3
// baseline (280.423 us; speedup 1.0000x reference)
//
#include <hip/hip_runtime.h>
#include <hip/hip_bf16.h>
#include <math.h>

// Problem constants
#define B_ 8
#define C_ 64
#define H_ 256
#define W_ 256
#define HL_ 128
#define WL_ 128
#define GN_G 8
#define CPG 8
#define GRP 4
#define OC_ 8
#define GROUP_ELEMS (CPG * H_ * W_)   // 524288

#define TILE_H 16       // low-res rows per k2 block
#define XROWS 34        // hi-res rows staged (2*16 + 2 halo)
#define LDSW 264        // LDS row stride in floats (16B-aligned stores at col 4)

// ---------------- Kernel 2': fused GN-partials + pool(x) + pool(L(x)) ----------------
// grid: (b,c) * 8 row-tiles = 4096 blocks, 256 threads
__global__ __launch_bounds__(256) void k2_fused(const float* __restrict__ x,
                                                const float* __restrict__ hpw,
                                                float* __restrict__ px,
                                                float* __restrict__ pL,
                                                float* __restrict__ partials) {
  __shared__ float tile[XROWS * LDSW];   // ~35.9 KB
  __shared__ float rs[4], rs2[4];
  const int t = threadIdx.x;
  const int blk = blockIdx.x;
  const int tileIdx = blk & 7;
  const int bc = blk >> 3;               // b*64+c
  const int c = bc & 63;
  const int hl0 = tileIdx * TILE_H;
  const float* plane = x + (size_t)bc * (H_ * W_);
  const int y0 = 2 * hl0 - 1;

  // zero the two sentinel columns (col 3 <-> x=-1, col 260 <-> x=256)
  if (t < XROWS * 2) {
    const int r = t >> 1;
    tile[r * LDSW + ((t & 1) ? 260 : 3)] = 0.f;
  }

  // stage x rows [y0, y0+33] as float4, accumulate GN partial sums on owned rows
  float s = 0.f, s2 = 0.f;
  for (int i = 0; i < 9; ++i) {
    const int q = t + i * 256;
    if (q >= XROWS * 64) break;
    const int r = q >> 6;
    const int c4 = (q & 63) << 2;
    const int y = y0 + r;
    float4 v = make_float4(0.f, 0.f, 0.f, 0.f);
    if ((unsigned)y < (unsigned)H_)
      v = *reinterpret_cast<const float4*>(plane + y * W_ + c4);
    *reinterpret_cast<float4*>(&tile[r * LDSW + 4 + c4]) = v;
    if (r >= 1 && r <= 32) {   // owned rows: exactly hi-res rows 2*hl0 .. 2*hl0+31
      s  += v.x + v.y + v.z + v.w;
      s2 += v.x * v.x + v.y * v.y + v.z * v.z + v.w * v.w;
    }
  }
#pragma unroll
  for (int off = 32; off > 0; off >>= 1) {
    s  += __shfl_down(s, off, 64);
    s2 += __shfl_down(s2, off, 64);
  }
  if ((t & 63) == 0) { rs[t >> 6] = s; rs2[t >> 6] = s2; }
  __syncthreads();
  if (t == 0) {
    partials[blk * 2 + 0] = rs[0] + rs[1] + rs[2] + rs[3];
    partials[blk * 2 + 1] = rs2[0] + rs2[1] + rs2[2] + rs2[3];
  }

  // depthwise weights (wave-uniform: c uniform per block)
  float w[9];
#pragma unroll
  for (int i = 0; i < 9; ++i) w[i] = hpw[c * 9 + i];

  // compute 8 vertical outputs per thread from LDS with rolling 4x4 window
  const int wl = t & 127;
  const int hs = (t >> 7) * 8;           // 0 or 8
  const int colb = 3 + 2 * wl;
  const int rbase = 2 * hs;
  float win[4][4];
#pragma unroll
  for (int j = 0; j < 4; ++j)
#pragma unroll
    for (int d = 0; d < 4; ++d)
      win[j][d] = tile[(rbase + j) * LDSW + colb + d];

  int outIdx = (bc * HL_ + (hl0 + hs)) * WL_ + wl;
#pragma unroll
  for (int i = 0; i < 8; ++i) {
    float pr[4][3];
#pragma unroll
    for (int j = 0; j < 4; ++j)
#pragma unroll
      for (int d = 0; d < 3; ++d) pr[j][d] = win[j][d] + win[j][d + 1];
    float hfsum = 0.f;
    float q11 = 0.f;
#pragma unroll
    for (int j = 0; j < 3; ++j)
#pragma unroll
      for (int d = 0; d < 3; ++d) {
        const float qq = pr[j][d] + pr[j + 1][d];
        hfsum = fmaf(w[j * 3 + d], qq, hfsum);
        if (j == 1 && d == 1) q11 = qq;
      }
    px[outIdx] = 0.25f * q11;
    pL[outIdx] = 0.25f * hfsum;
    outIdx += WL_;
    if (i < 7) {
      const int rn = rbase + 2 * i + 4;
#pragma unroll
      for (int d = 0; d < 4; ++d) {
        win[0][d] = win[2][d];
        win[1][d] = win[3][d];
        win[2][d] = tile[rn * LDSW + colb + d];
        win[3][d] = tile[(rn + 1) * LDSW + colb + d];
      }
    }
  }
}

// ---------------- Kernel 1b: finalize per-(b,c) affine ----------------
__global__ __launch_bounds__(512) void k1_finish(const float* __restrict__ partials,
                                                 const float* __restrict__ gamma,
                                                 const float* __restrict__ beta,
                                                 float* __restrict__ ab) {
  const int t = threadIdx.x;
  const int b = t >> 6, c = t & 63, g = c >> 3;
  float S = 0.f, S2 = 0.f;
  for (int c2 = g * CPG; c2 < g * CPG + CPG; ++c2)
#pragma unroll
    for (int p = 0; p < 8; ++p) {
      const int blk = (b * 64 + c2) * 8 + p;
      S  += partials[blk * 2 + 0];
      S2 += partials[blk * 2 + 1];
    }
  const float N = (float)GROUP_ELEMS;
  const float mean = S / N;
  const float var = fmaxf(S2 / N - mean * mean, 0.f);
  const float a = rsqrtf(var + 1e-5f) * gamma[c];
  ab[t * 2 + 0] = a;
  ab[t * 2 + 1] = beta[c] - mean * a;
}

// ---------------- Kernel 3'': 4-way channel-split direction feat + gates -> grid ----------------
// 4 lanes per low-res pixel; lane cg handles channels c = 4j+cg, j=0..15.
// grid: 2048 blocks x 256 threads (64 pixels/block).
__global__ __launch_bounds__(256) void k3_offset(const float* __restrict__ px,
                                                 const float* __restrict__ pL,
                                                 const float* __restrict__ ab,
                                                 const float* __restrict__ dir_w,
                                                 const float* __restrict__ dir_b,
                                                 const float* __restrict__ mag_w,
                                                 const float* __restrict__ mag_b,
                                                 const float* __restrict__ hfg_w,
                                                 const float* __restrict__ hfg_b,
                                                 float2* __restrict__ grid) {
  __shared__ float s_mw[C_][OC_];    // transposed mag_w: [c][o]
  __shared__ float s_hw[C_][OC_];    // transposed hfg_w
  __shared__ float s_dir[OC_][8];
  __shared__ float s_ab2[C_][2];
  __shared__ float s_bias[2][OC_];   // [0]: mag_b+hfg_b, [1]: dir_b
  const int tid = threadIdx.x;
  const int pix = blockIdx.x * 64 + (tid >> 2);
  const int cg = tid & 3;
  const int wl = pix & (WL_ - 1);
  const int hl = (pix >> 7) & (HL_ - 1);
  const int b = pix >> 14;                 // uniform per block (64 | 16384)

  for (int i = tid; i < OC_ * C_; i += 256) {
    const int o = i >> 6, c = i & 63;
    s_mw[c][o] = mag_w[i];
    s_hw[c][o] = hfg_w[i];
  }
  if (tid < 64) s_dir[tid >> 3][tid & 7] = dir_w[tid];
  if (tid < 128) s_ab2[tid >> 1][tid & 1] = ab[b * 128 + tid];
  if (tid < OC_) { s_bias[0][tid] = mag_b[tid] + hfg_b[tid]; s_bias[1][tid] = dir_b[tid]; }
  __syncthreads();

  const bool up = hl > 0, dn = hl < HL_ - 1, lf = wl > 0, rt = wl < WL_ - 1;
  const bool OK[8] = {up && lf, up, up && rt, lf, rt, dn && lf, dn, dn && rt};
  const int NOFF[8] = {-WL_ - 1, -WL_, -WL_ + 1, -1, 1, WL_ - 1, WL_, WL_ + 1};
  const float mterm = 0.5f * ((hl == 0) + (hl == HL_ - 1) + (wl == 0) + (wl == WL_ - 1));

  float dot[8], n2[8], z[8], n1 = 0.f;
#pragma unroll
  for (int k = 0; k < 8; ++k) { dot[k] = 0.f; n2[k] = 0.f; z[k] = 0.f; }

  int poff = ((b * C_ + cg) * HL_ + hl) * WL_ + wl;
#pragma unroll
  for (int j = 0; j < 16; ++j) {
    const int c = 4 * j + cg;
    const float a = s_ab2[c][0];
    const float bb = s_ab2[c][1];
    const float* p = px + poff;
    const float vc = fmaf(a, p[0], bb);
    const float vh = fmaf(a, pL[poff], bb * mterm);
    n1 = fmaf(vc, vc, n1);
#pragma unroll
    for (int k = 0; k < 8; ++k) {
      const float v = OK[k] ? fmaf(a, p[NOFF[k]], bb) : 0.f;   // in-bounds of ws even when masked
      dot[k] = fmaf(vc, v, dot[k]);
      n2[k] = fmaf(v, v, n2[k]);
    }
    const float4 mw0 = *reinterpret_cast<const float4*>(&s_mw[c][0]);
    const float4 mw1 = *reinterpret_cast<const float4*>(&s_mw[c][4]);
    const float4 hw0 = *reinterpret_cast<const float4*>(&s_hw[c][0]);
    const float4 hw1 = *reinterpret_cast<const float4*>(&s_hw[c][4]);
    z[0] = fmaf(mw0.x, vc, fmaf(hw0.x, vh, z[0]));
    z[1] = fmaf(mw0.y, vc, fmaf(hw0.y, vh, z[1]));
    z[2] = fmaf(mw0.z, vc, fmaf(hw0.z, vh, z[2]));
    z[3] = fmaf(mw0.w, vc, fmaf(hw0.w, vh, z[3]));
    z[4] = fmaf(mw1.x, vc, fmaf(hw1.x, vh, z[4]));
    z[5] = fmaf(mw1.y, vc, fmaf(hw1.y, vh, z[5]));
    z[6] = fmaf(mw1.z, vc, fmaf(hw1.z, vh, z[6]));
    z[7] = fmaf(mw1.w, vc, fmaf(hw1.w, vh, z[7]));
    poff += 4 * HL_ * WL_;
  }

  // reduce across the 4-lane channel groups (all lanes end with full sums)
#pragma unroll
  for (int k = 0; k < 8; ++k) {
    dot[k] += __shfl_xor(dot[k], 1); dot[k] += __shfl_xor(dot[k], 2);
    n2[k]  += __shfl_xor(n2[k], 1);  n2[k]  += __shfl_xor(n2[k], 2);
    z[k]   += __shfl_xor(z[k], 1);   z[k]   += __shfl_xor(z[k], 2);
  }
  n1 += __shfl_xor(n1, 1); n1 += __shfl_xor(n1, 2);

  const float n1c = fmaxf(sqrtf(n1), 1e-8f);
  float df[8];
#pragma unroll
  for (int k = 0; k < 8; ++k)
    df[k] = dot[k] / (n1c * fmaxf(sqrtf(n2[k]), 1e-8f));

  // lane cg computes group g=cg: offsets o=cg (x) and o=cg+4 (y)
  float offx = s_bias[1][cg], offy = s_bias[1][cg + 4];
#pragma unroll
  for (int jj = 0; jj < 8; ++jj) {
    offx = fmaf(s_dir[cg][jj], df[jj], offx);
    offy = fmaf(s_dir[cg + 4][jj], df[jj], offy);
  }
  const float zx = ((cg == 0) ? z[0] : (cg == 1) ? z[1] : (cg == 2) ? z[2] : z[3]) + s_bias[0][cg];
  const float zy = ((cg == 0) ? z[4] : (cg == 1) ? z[5] : (cg == 2) ? z[6] : z[7]) + s_bias[0][cg + 4];
  offx *= 1.f / (1.f + expf(-zx));
  offy *= 1.f / (1.f + expf(-zy));

  const float ix = fminf(fmaxf(2.f * wl + 0.5f + offx, 0.f), (float)(W_ - 1));
  const float iy = fminf(fmaxf(2.f * hl + 0.5f + offy, 0.f), (float)(H_ - 1));
  grid[(b * GRP + cg) * (HL_ * WL_) + hl * WL_ + wl] = make_float2(ix, iy);
}

// ---------------- Kernel 4: bilinear grid sample (border) ----------------
__global__ __launch_bounds__(256) void k4_sample(const float* __restrict__ x,
                                                 const float2* __restrict__ grid,
                                                 float* __restrict__ out) {
  const int idx = blockIdx.x * 256 + threadIdx.x;
  const int wl = idx & (WL_ - 1);
  const int hl = (idx >> 7) & (HL_ - 1);
  const int bc = idx >> 14;
  const int c = bc & 63;
  const int b = bc >> 6;
  const int g = c >> 4;
  const float2 G = grid[(b * GRP + g) * (HL_ * WL_) + hl * WL_ + wl];
  const float ix = G.x, iy = G.y;
  const float x0f = floorf(ix), y0f = floorf(iy);
  const float wx = ix - x0f, wy = iy - y0f;
  const int x0 = (int)x0f, y0 = (int)y0f;
  const int x1 = min(x0 + 1, W_ - 1), y1 = min(y0 + 1, H_ - 1);
  const float* plane = x + (size_t)bc * (H_ * W_);
  const float v00 = plane[y0 * W_ + x0];
  const float v01 = plane[y0 * W_ + x1];
  const float v10 = plane[y1 * W_ + x0];
  const float v11 = plane[y1 * W_ + x1];
  out[idx] = v00 * (1.f - wx) * (1.f - wy) + v01 * wx * (1.f - wy)
           + v10 * (1.f - wx) * wy + v11 * wx * wy;
}

extern "C" void kernel_launch(void* const* d_in, const int* in_sizes, int n_in,
                              void* d_out, int out_size, void* d_ws, size_t ws_size,
                              hipStream_t stream) {
  const float* x = (const float*)d_in[0];
  const float* gn_gamma = (const float*)d_in[1];
  const float* gn_beta = (const float*)d_in[2];
  const float* hp_weight = (const float*)d_in[3];
  const float* dir_w = (const float*)d_in[4];
  const float* dir_b = (const float*)d_in[5];
  const float* mag_w = (const float*)d_in[6];
  const float* mag_b = (const float*)d_in[7];
  const float* hfg_w = (const float*)d_in[8];
  const float* hfg_b = (const float*)d_in[9];
  float* out = (float*)d_out;

  // ws layout (floats)
  float* ws = (float*)d_ws;
  float* partials = ws;                                  // 8192
  float* ab = ws + 8192;                                 // 1024
  float* px = ws + 16384;                                // 2,097,152
  float* pL = px + (size_t)B_ * C_ * HL_ * WL_;          // 2,097,152
  float2* grid = (float2*)(pL + (size_t)B_ * C_ * HL_ * WL_);  // 1,048,576 floats

  k2_fused<<<B_ * C_ * 8, 256, 0, stream>>>(x, hp_weight, px, pL, partials);
  k1_finish<<<1, 512, 0, stream>>>(partials, gn_gamma, gn_beta, ab);
  k3_offset<<<(B_ * HL_ * WL_) / 64, 256, 0, stream>>>(px, pL, ab, dir_w, dir_b,
                                                       mag_w, mag_b, hfg_w, hfg_b, grid);
  k4_sample<<<(B_ * C_ * HL_ * WL_) / 256, 256, 0, stream>>>(x, grid, out);
}

// Round 5
// 131.728 us; speedup vs baseline: 2.1288x; 2.1288x over previous
//
#include <hip/hip_runtime.h>
#include <hip/hip_bf16.h>
#include <math.h>

// Problem constants
#define B_ 8
#define C_ 64
#define H_ 256
#define W_ 256
#define HL_ 128
#define WL_ 128
#define GN_G 8
#define CPG 8
#define GRP 4
#define OC_ 8
#define GROUP_ELEMS (CPG * H_ * W_)   // 524288

#define TILE_H 16       // low-res rows per k2 block
#define XROWS 34        // hi-res rows staged (2*16 + 2 halo)
#define LDSW 264        // LDS row stride in floats (16B-aligned stores at col 4)

// ---------------- Kernel 2': fused GN-partials + pool(x) + pool(L(x)) ----------------
// grid: (b,c) * 8 row-tiles = 4096 blocks, 256 threads
__global__ __launch_bounds__(256) void k2_fused(const float* __restrict__ x,
                                                const float* __restrict__ hpw,
                                                float* __restrict__ px,
                                                float* __restrict__ pL,
                                                float* __restrict__ partials) {
  __shared__ float tile[XROWS * LDSW];   // ~35.9 KB
  __shared__ float rs[4], rs2[4];
  const int t = threadIdx.x;
  const int blk = blockIdx.x;
  const int tileIdx = blk & 7;
  const int bc = blk >> 3;               // b*64+c
  const int c = bc & 63;
  const int hl0 = tileIdx * TILE_H;
  const float* plane = x + (size_t)bc * (H_ * W_);
  const int y0 = 2 * hl0 - 1;

  // zero the two sentinel columns (col 3 <-> x=-1, col 260 <-> x=256)
  if (t < XROWS * 2) {
    const int r = t >> 1;
    tile[r * LDSW + ((t & 1) ? 260 : 3)] = 0.f;
  }

  // stage x rows [y0, y0+33] as float4, accumulate GN partial sums on owned rows
  float s = 0.f, s2 = 0.f;
  for (int i = 0; i < 9; ++i) {
    const int q = t + i * 256;
    if (q >= XROWS * 64) break;
    const int r = q >> 6;
    const int c4 = (q & 63) << 2;
    const int y = y0 + r;
    float4 v = make_float4(0.f, 0.f, 0.f, 0.f);
    if ((unsigned)y < (unsigned)H_)
      v = *reinterpret_cast<const float4*>(plane + y * W_ + c4);
    *reinterpret_cast<float4*>(&tile[r * LDSW + 4 + c4]) = v;
    if (r >= 1 && r <= 32) {   // owned rows: exactly hi-res rows 2*hl0 .. 2*hl0+31
      s  += v.x + v.y + v.z + v.w;
      s2 += v.x * v.x + v.y * v.y + v.z * v.z + v.w * v.w;
    }
  }
#pragma unroll
  for (int off = 32; off > 0; off >>= 1) {
    s  += __shfl_down(s, off, 64);
    s2 += __shfl_down(s2, off, 64);
  }
  if ((t & 63) == 0) { rs[t >> 6] = s; rs2[t >> 6] = s2; }
  __syncthreads();
  if (t == 0) {
    partials[blk * 2 + 0] = rs[0] + rs[1] + rs[2] + rs[3];
    partials[blk * 2 + 1] = rs2[0] + rs2[1] + rs2[2] + rs2[3];
  }

  // depthwise weights (wave-uniform: c uniform per block)
  float w[9];
#pragma unroll
  for (int i = 0; i < 9; ++i) w[i] = hpw[c * 9 + i];

  // compute 8 vertical outputs per thread from LDS with rolling 4x4 window
  const int wl = t & 127;
  const int hs = (t >> 7) * 8;           // 0 or 8
  const int colb = 3 + 2 * wl;
  const int rbase = 2 * hs;
  float win[4][4];
#pragma unroll
  for (int j = 0; j < 4; ++j)
#pragma unroll
    for (int d = 0; d < 4; ++d)
      win[j][d] = tile[(rbase + j) * LDSW + colb + d];

  int outIdx = (bc * HL_ + (hl0 + hs)) * WL_ + wl;
#pragma unroll
  for (int i = 0; i < 8; ++i) {
    float pr[4][3];
#pragma unroll
    for (int j = 0; j < 4; ++j)
#pragma unroll
      for (int d = 0; d < 3; ++d) pr[j][d] = win[j][d] + win[j][d + 1];
    float hfsum = 0.f;
    float q11 = 0.f;
#pragma unroll
    for (int j = 0; j < 3; ++j)
#pragma unroll
      for (int d = 0; d < 3; ++d) {
        const float qq = pr[j][d] + pr[j + 1][d];
        hfsum = fmaf(w[j * 3 + d], qq, hfsum);
        if (j == 1 && d == 1) q11 = qq;
      }
    px[outIdx] = 0.25f * q11;
    pL[outIdx] = 0.25f * hfsum;
    outIdx += WL_;
    if (i < 7) {
      const int rn = rbase + 2 * i + 4;
#pragma unroll
      for (int d = 0; d < 4; ++d) {
        win[0][d] = win[2][d];
        win[1][d] = win[3][d];
        win[2][d] = tile[rn * LDSW + colb + d];
        win[3][d] = tile[(rn + 1) * LDSW + colb + d];
      }
    }
  }
}

// ---------------- Kernel 1b: finalize per-(b,c) affine ----------------
__global__ __launch_bounds__(512) void k1_finish(const float* __restrict__ partials,
                                                 const float* __restrict__ gamma,
                                                 const float* __restrict__ beta,
                                                 float* __restrict__ ab) {
  const int t = threadIdx.x;
  const int b = t >> 6, c = t & 63, g = c >> 3;
  float S = 0.f, S2 = 0.f;
  for (int c2 = g * CPG; c2 < g * CPG + CPG; ++c2)
#pragma unroll
    for (int p = 0; p < 8; ++p) {
      const int blk = (b * 64 + c2) * 8 + p;
      S  += partials[blk * 2 + 0];
      S2 += partials[blk * 2 + 1];
    }
  const float N = (float)GROUP_ELEMS;
  const float mean = S / N;
  const float var = fmaxf(S2 / N - mean * mean, 0.f);
  const float a = rsqrtf(var + 1e-5f) * gamma[c];
  ab[t * 2 + 0] = a;
  ab[t * 2 + 1] = beta[c] - mean * a;
}

// ---------------- Kernel 3''': 4-way channel-split, register-lean ----------------
// 4 lanes per low-res pixel; lane cg handles channels c = 4j+cg, j=0..15 (rolled loop).
// grid: 2048 blocks x 256 threads (64 pixels/block) -> 8192 waves.
__global__ __launch_bounds__(256, 8) void k3_offset(const float* __restrict__ px,
                                                    const float* __restrict__ pL,
                                                    const float* __restrict__ ab,
                                                    const float* __restrict__ dir_w,
                                                    const float* __restrict__ dir_b,
                                                    const float* __restrict__ mag_w,
                                                    const float* __restrict__ mag_b,
                                                    const float* __restrict__ hfg_w,
                                                    const float* __restrict__ hfg_b,
                                                    float2* __restrict__ grid) {
  __shared__ float s_mw[C_][OC_];    // transposed mag_w: [c][o]
  __shared__ float s_hw[C_][OC_];    // transposed hfg_w
  __shared__ float s_dir[OC_][8];
  __shared__ float s_ab2[C_][2];
  __shared__ float s_bias[2][OC_];   // [0]: mag_b+hfg_b, [1]: dir_b
  const int tid = threadIdx.x;
  const int pix = blockIdx.x * 64 + (tid >> 2);
  const int cg = tid & 3;
  const int wl = pix & (WL_ - 1);
  const int hl = (pix >> 7) & (HL_ - 1);
  const int b = pix >> 14;                 // uniform per block (64 | 16384)

  for (int i = tid; i < OC_ * C_; i += 256) {
    const int o = i >> 6, c = i & 63;
    s_mw[c][o] = mag_w[i];
    s_hw[c][o] = hfg_w[i];
  }
  if (tid < 64) s_dir[tid >> 3][tid & 7] = dir_w[tid];
  if (tid < 128) s_ab2[tid >> 1][tid & 1] = ab[b * 128 + tid];
  if (tid < OC_) { s_bias[0][tid] = mag_b[tid] + hfg_b[tid]; s_bias[1][tid] = dir_b[tid]; }
  __syncthreads();

  const bool up = hl > 0, dn = hl < HL_ - 1, lf = wl > 0, rt = wl < WL_ - 1;
  const float mterm = 0.5f * ((hl == 0) + (hl == HL_ - 1) + (wl == 0) + (wl == WL_ - 1));

  float dot[8], n2[8], z[8], n1 = 0.f;
#pragma unroll
  for (int k = 0; k < 8; ++k) { dot[k] = 0.f; n2[k] = 0.f; z[k] = 0.f; }

  int poff = ((b * C_ + cg) * HL_ + hl) * WL_ + wl;
#pragma unroll 1
  for (int j = 0; j < 16; ++j) {
    const int c = 4 * j + cg;
    const float a = s_ab2[c][0];
    const float bb = s_ab2[c][1];
    const float* p = px + poff;
    // issue all 10 independent loads up front
    const float lc = p[0];
    const float lh = pL[poff];
    const float l0 = p[-WL_ - 1];
    const float l1 = p[-WL_];
    const float l2 = p[-WL_ + 1];
    const float l3 = p[-1];
    const float l4 = p[1];
    const float l5 = p[WL_ - 1];
    const float l6 = p[WL_];
    const float l7 = p[WL_ + 1];
    const float vc = fmaf(a, lc, bb);
    const float vh = fmaf(a, lh, bb * mterm);
    n1 = fmaf(vc, vc, n1);
    const float v0 = (up && lf) ? fmaf(a, l0, bb) : 0.f;
    const float v1 = up         ? fmaf(a, l1, bb) : 0.f;
    const float v2 = (up && rt) ? fmaf(a, l2, bb) : 0.f;
    const float v3 = lf         ? fmaf(a, l3, bb) : 0.f;
    const float v4 = rt         ? fmaf(a, l4, bb) : 0.f;
    const float v5 = (dn && lf) ? fmaf(a, l5, bb) : 0.f;
    const float v6 = dn         ? fmaf(a, l6, bb) : 0.f;
    const float v7 = (dn && rt) ? fmaf(a, l7, bb) : 0.f;
    dot[0] = fmaf(vc, v0, dot[0]); n2[0] = fmaf(v0, v0, n2[0]);
    dot[1] = fmaf(vc, v1, dot[1]); n2[1] = fmaf(v1, v1, n2[1]);
    dot[2] = fmaf(vc, v2, dot[2]); n2[2] = fmaf(v2, v2, n2[2]);
    dot[3] = fmaf(vc, v3, dot[3]); n2[3] = fmaf(v3, v3, n2[3]);
    dot[4] = fmaf(vc, v4, dot[4]); n2[4] = fmaf(v4, v4, n2[4]);
    dot[5] = fmaf(vc, v5, dot[5]); n2[5] = fmaf(v5, v5, n2[5]);
    dot[6] = fmaf(vc, v6, dot[6]); n2[6] = fmaf(v6, v6, n2[6]);
    dot[7] = fmaf(vc, v7, dot[7]); n2[7] = fmaf(v7, v7, n2[7]);
#pragma unroll
    for (int o = 0; o < 8; ++o)
      z[o] = fmaf(s_mw[c][o], vc, fmaf(s_hw[c][o], vh, z[o]));
    poff += 4 * HL_ * WL_;
  }

  // reduce across the 4-lane channel groups (all lanes end with full sums)
#pragma unroll
  for (int k = 0; k < 8; ++k) {
    dot[k] += __shfl_xor(dot[k], 1); dot[k] += __shfl_xor(dot[k], 2);
    n2[k]  += __shfl_xor(n2[k], 1);  n2[k]  += __shfl_xor(n2[k], 2);
    z[k]   += __shfl_xor(z[k], 1);   z[k]   += __shfl_xor(z[k], 2);
  }
  n1 += __shfl_xor(n1, 1); n1 += __shfl_xor(n1, 2);

  const float n1c = fmaxf(sqrtf(n1), 1e-8f);
  float df[8];
#pragma unroll
  for (int k = 0; k < 8; ++k)
    df[k] = dot[k] / (n1c * fmaxf(sqrtf(n2[k]), 1e-8f));

  // lane cg computes group g=cg: offsets o=cg (x) and o=cg+4 (y)
  float offx = s_bias[1][cg], offy = s_bias[1][cg + 4];
#pragma unroll
  for (int jj = 0; jj < 8; ++jj) {
    offx = fmaf(s_dir[cg][jj], df[jj], offx);
    offy = fmaf(s_dir[cg + 4][jj], df[jj], offy);
  }
  const float zx = ((cg == 0) ? z[0] : (cg == 1) ? z[1] : (cg == 2) ? z[2] : z[3]) + s_bias[0][cg];
  const float zy = ((cg == 0) ? z[4] : (cg == 1) ? z[5] : (cg == 2) ? z[6] : z[7]) + s_bias[0][cg + 4];
  offx *= 1.f / (1.f + expf(-zx));
  offy *= 1.f / (1.f + expf(-zy));

  const float ix = fminf(fmaxf(2.f * wl + 0.5f + offx, 0.f), (float)(W_ - 1));
  const float iy = fminf(fmaxf(2.f * hl + 0.5f + offy, 0.f), (float)(H_ - 1));
  grid[(b * GRP + cg) * (HL_ * WL_) + hl * WL_ + wl] = make_float2(ix, iy);
}

// ---------------- Kernel 4: bilinear grid sample (border) ----------------
__global__ __launch_bounds__(256) void k4_sample(const float* __restrict__ x,
                                                 const float2* __restrict__ grid,
                                                 float* __restrict__ out) {
  const int idx = blockIdx.x * 256 + threadIdx.x;
  const int wl = idx & (WL_ - 1);
  const int hl = (idx >> 7) & (HL_ - 1);
  const int bc = idx >> 14;
  const int c = bc & 63;
  const int b = bc >> 6;
  const int g = c >> 4;
  const float2 G = grid[(b * GRP + g) * (HL_ * WL_) + hl * WL_ + wl];
  const float ix = G.x, iy = G.y;
  const float x0f = floorf(ix), y0f = floorf(iy);
  const float wx = ix - x0f, wy = iy - y0f;
  const int x0 = (int)x0f, y0 = (int)y0f;
  const int x1 = min(x0 + 1, W_ - 1), y1 = min(y0 + 1, H_ - 1);
  const float* plane = x + (size_t)bc * (H_ * W_);
  const float v00 = plane[y0 * W_ + x0];
  const float v01 = plane[y0 * W_ + x1];
  const float v10 = plane[y1 * W_ + x0];
  const float v11 = plane[y1 * W_ + x1];
  out[idx] = v00 * (1.f - wx) * (1.f - wy) + v01 * wx * (1.f - wy)
           + v10 * (1.f - wx) * wy + v11 * wx * wy;
}

extern "C" void kernel_launch(void* const* d_in, const int* in_sizes, int n_in,
                              void* d_out, int out_size, void* d_ws, size_t ws_size,
                              hipStream_t stream) {
  const float* x = (const float*)d_in[0];
  const float* gn_gamma = (const float*)d_in[1];
  const float* gn_beta = (const float*)d_in[2];
  const float* hp_weight = (const float*)d_in[3];
  const float* dir_w = (const float*)d_in[4];
  const float* dir_b = (const float*)d_in[5];
  const float* mag_w = (const float*)d_in[6];
  const float* mag_b = (const float*)d_in[7];
  const float* hfg_w = (const float*)d_in[8];
  const float* hfg_b = (const float*)d_in[9];
  float* out = (float*)d_out;

  // ws layout (floats)
  float* ws = (float*)d_ws;
  float* partials = ws;                                  // 8192
  float* ab = ws + 8192;                                 // 1024
  float* px = ws + 16384;                                // 2,097,152
  float* pL = px + (size_t)B_ * C_ * HL_ * WL_;          // 2,097,152
  float2* grid = (float2*)(pL + (size_t)B_ * C_ * HL_ * WL_);  // 1,048,576 floats

  k2_fused<<<B_ * C_ * 8, 256, 0, stream>>>(x, hp_weight, px, pL, partials);
  k1_finish<<<1, 512, 0, stream>>>(partials, gn_gamma, gn_beta, ab);
  k3_offset<<<(B_ * HL_ * WL_) / 64, 256, 0, stream>>>(px, pL, ab, dir_w, dir_b,
                                                       mag_w, mag_b, hfg_w, hfg_b, grid);
  k4_sample<<<(B_ * C_ * HL_ * WL_) / 256, 256, 0, stream>>>(x, grid, out);
}

// Round 6
// 111.701 us; speedup vs baseline: 2.5105x; 1.1793x over previous
//
#include <hip/hip_runtime.h>
#include <hip/hip_bf16.h>
#include <math.h>

// Problem constants
#define B_ 8
#define C_ 64
#define H_ 256
#define W_ 256
#define HL_ 128
#define WL_ 128
#define GN_G 8
#define CPG 8
#define GRP 4
#define OC_ 8
#define GROUP_ELEMS (CPG * H_ * W_)   // 524288

#define TILE_H 16       // low-res rows per k2 block
#define XROWS 34        // hi-res rows staged (2*16 + 2 halo)
#define LDSW 264        // LDS row stride in floats (16B-aligned stores at col 4)

// ---------------- Kernel 2': fused GN-partials + pool(x) + pool(L(x)) ----------------
// grid: (b,c) * 8 row-tiles = 4096 blocks, 256 threads
__global__ __launch_bounds__(256) void k2_fused(const float* __restrict__ x,
                                                const float* __restrict__ hpw,
                                                float* __restrict__ px,
                                                float* __restrict__ pL,
                                                float* __restrict__ partials) {
  __shared__ float tile[XROWS * LDSW];   // ~35.9 KB
  __shared__ float rs[4], rs2[4];
  const int t = threadIdx.x;
  const int blk = blockIdx.x;
  const int tileIdx = blk & 7;
  const int bc = blk >> 3;               // b*64+c
  const int c = bc & 63;
  const int hl0 = tileIdx * TILE_H;
  const float* plane = x + (size_t)bc * (H_ * W_);
  const int y0 = 2 * hl0 - 1;

  // zero the two sentinel columns (col 3 <-> x=-1, col 260 <-> x=256)
  if (t < XROWS * 2) {
    const int r = t >> 1;
    tile[r * LDSW + ((t & 1) ? 260 : 3)] = 0.f;
  }

  // stage x rows [y0, y0+33] as float4, accumulate GN partial sums on owned rows
  float s = 0.f, s2 = 0.f;
  for (int i = 0; i < 9; ++i) {
    const int q = t + i * 256;
    if (q >= XROWS * 64) break;
    const int r = q >> 6;
    const int c4 = (q & 63) << 2;
    const int y = y0 + r;
    float4 v = make_float4(0.f, 0.f, 0.f, 0.f);
    if ((unsigned)y < (unsigned)H_)
      v = *reinterpret_cast<const float4*>(plane + y * W_ + c4);
    *reinterpret_cast<float4*>(&tile[r * LDSW + 4 + c4]) = v;
    if (r >= 1 && r <= 32) {   // owned rows: exactly hi-res rows 2*hl0 .. 2*hl0+31
      s  += v.x + v.y + v.z + v.w;
      s2 += v.x * v.x + v.y * v.y + v.z * v.z + v.w * v.w;
    }
  }
#pragma unroll
  for (int off = 32; off > 0; off >>= 1) {
    s  += __shfl_down(s, off, 64);
    s2 += __shfl_down(s2, off, 64);
  }
  if ((t & 63) == 0) { rs[t >> 6] = s; rs2[t >> 6] = s2; }
  __syncthreads();
  if (t == 0) {
    partials[blk * 2 + 0] = rs[0] + rs[1] + rs[2] + rs[3];
    partials[blk * 2 + 1] = rs2[0] + rs2[1] + rs2[2] + rs2[3];
  }

  // depthwise weights (wave-uniform: c uniform per block)
  float w[9];
#pragma unroll
  for (int i = 0; i < 9; ++i) w[i] = hpw[c * 9 + i];

  // compute 8 vertical outputs per thread from LDS with rolling 4x4 window
  const int wl = t & 127;
  const int hs = (t >> 7) * 8;           // 0 or 8
  const int colb = 3 + 2 * wl;
  const int rbase = 2 * hs;
  float win[4][4];
#pragma unroll
  for (int j = 0; j < 4; ++j)
#pragma unroll
    for (int d = 0; d < 4; ++d)
      win[j][d] = tile[(rbase + j) * LDSW + colb + d];

  int outIdx = (bc * HL_ + (hl0 + hs)) * WL_ + wl;
#pragma unroll
  for (int i = 0; i < 8; ++i) {
    float pr[4][3];
#pragma unroll
    for (int j = 0; j < 4; ++j)
#pragma unroll
      for (int d = 0; d < 3; ++d) pr[j][d] = win[j][d] + win[j][d + 1];
    float hfsum = 0.f;
    float q11 = 0.f;
#pragma unroll
    for (int j = 0; j < 3; ++j)
#pragma unroll
      for (int d = 0; d < 3; ++d) {
        const float qq = pr[j][d] + pr[j + 1][d];
        hfsum = fmaf(w[j * 3 + d], qq, hfsum);
        if (j == 1 && d == 1) q11 = qq;
      }
    px[outIdx] = 0.25f * q11;
    pL[outIdx] = 0.25f * hfsum;
    outIdx += WL_;
    if (i < 7) {
      const int rn = rbase + 2 * i + 4;
#pragma unroll
      for (int d = 0; d < 4; ++d) {
        win[0][d] = win[2][d];
        win[1][d] = win[3][d];
        win[2][d] = tile[rn * LDSW + colb + d];
        win[3][d] = tile[(rn + 1) * LDSW + colb + d];
      }
    }
  }
}

// ---------------- Kernel 1b: finalize per-(b,c) affine ----------------
__global__ __launch_bounds__(512) void k1_finish(const float* __restrict__ partials,
                                                 const float* __restrict__ gamma,
                                                 const float* __restrict__ beta,
                                                 float* __restrict__ ab) {
  const int t = threadIdx.x;
  const int b = t >> 6, c = t & 63, g = c >> 3;
  float S = 0.f, S2 = 0.f;
  for (int c2 = g * CPG; c2 < g * CPG + CPG; ++c2)
#pragma unroll
    for (int p = 0; p < 8; ++p) {
      const int blk = (b * 64 + c2) * 8 + p;
      S  += partials[blk * 2 + 0];
      S2 += partials[blk * 2 + 1];
    }
  const float N = (float)GROUP_ELEMS;
  const float mean = S / N;
  const float var = fmaxf(S2 / N - mean * mean, 0.f);
  const float a = rsqrtf(var + 1e-5f) * gamma[c];
  ab[t * 2 + 0] = a;
  ab[t * 2 + 1] = beta[c] - mean * a;
}

// ---------------- Kernel 3 (v4): LDS-tiled direction feat + gates -> grid ----------------
// One block = 16x16 pixel tile of one batch. 4 chunks of 16 channels staged in LDS
// with affine pre-applied and border-zero halo (absorbs neighbor masking).
// grid: 8 * 8 * 8 = 512 blocks x 256 threads, 1 pixel/thread.
#define TS 16
__global__ __launch_bounds__(256) void k3_offset(const float* __restrict__ px,
                                                 const float* __restrict__ pL,
                                                 const float* __restrict__ ab,
                                                 const float* __restrict__ dir_w,
                                                 const float* __restrict__ dir_b,
                                                 const float* __restrict__ mag_w,
                                                 const float* __restrict__ mag_b,
                                                 const float* __restrict__ hfg_w,
                                                 const float* __restrict__ hfg_b,
                                                 float2* __restrict__ grid) {
  __shared__ float s_v[16][18][24];   // affine xl tile + halo; col i <-> wl = wl0-4+i
  __shared__ float s_h[16][16][16];   // affine hfl tile (mterm folded)
  __shared__ float s_mw[C_][OC_];     // transposed mag_w
  __shared__ float s_hw[C_][OC_];     // transposed hfg_w
  __shared__ float s_dir[OC_][8];
  __shared__ float s_ab2[C_][2];
  __shared__ float s_bias[2][OC_];

  const int tid = threadIdx.x;
  const int bx = blockIdx.x;
  const int tx = bx & 7, ty = (bx >> 3) & 7, b = bx >> 6;
  const int hl0 = ty * TS, wl0 = tx * TS;

  for (int i = tid; i < OC_ * C_; i += 256) {
    const int o = i >> 6, c = i & 63;
    s_mw[c][o] = mag_w[i];
    s_hw[c][o] = hfg_w[i];
  }
  if (tid < 64) s_dir[tid >> 3][tid & 7] = dir_w[tid];
  if (tid < 128) s_ab2[tid >> 1][tid & 1] = ab[b * 128 + tid];
  if (tid < OC_) { s_bias[0][tid] = mag_b[tid] + hfg_b[tid]; s_bias[1][tid] = dir_b[tid]; }

  const int pxi = tid & 15, pyi = tid >> 4;
  const int hl = hl0 + pyi, wl = wl0 + pxi;

  float dot[8], n2[8], z[8], n1 = 0.f;
#pragma unroll
  for (int k = 0; k < 8; ++k) { dot[k] = 0.f; n2[k] = 0.f; z[k] = 0.f; }

  const size_t planeSz = (size_t)HL_ * WL_;
  for (int cc = 0; cc < 4; ++cc) {
    __syncthreads();   // protect LDS reuse across chunks
    // stage s_v: 16ch x 18rows x 6xfloat4 (zero outside image, affine applied)
    for (int q = tid; q < 16 * 18 * 6; q += 256) {
      const int c = q / 108, rem = q % 108, r = rem / 6, f4 = rem % 6;
      const int cg = cc * 16 + c;
      const int gy = hl0 - 1 + r;
      const int gx0 = wl0 - 4 + f4 * 4;
      const float a = s_ab2[cg][0], bb = s_ab2[cg][1];
      const float* pp = px + (size_t)(b * C_ + cg) * planeSz + gy * WL_ + gx0;
      float4 v = make_float4(0.f, 0.f, 0.f, 0.f);
      if ((unsigned)gy < (unsigned)HL_) {
        if (gx0 >= 0 && gx0 + 3 < WL_) {
          v = *reinterpret_cast<const float4*>(pp);
          v.x = fmaf(a, v.x, bb); v.y = fmaf(a, v.y, bb);
          v.z = fmaf(a, v.z, bb); v.w = fmaf(a, v.w, bb);
        } else {
          if ((unsigned)(gx0 + 0) < (unsigned)WL_) v.x = fmaf(a, pp[0], bb);
          if ((unsigned)(gx0 + 1) < (unsigned)WL_) v.y = fmaf(a, pp[1], bb);
          if ((unsigned)(gx0 + 2) < (unsigned)WL_) v.z = fmaf(a, pp[2], bb);
          if ((unsigned)(gx0 + 3) < (unsigned)WL_) v.w = fmaf(a, pp[3], bb);
        }
      }
      *reinterpret_cast<float4*>(&s_v[c][r][f4 * 4]) = v;
    }
    // stage s_h: 16ch x 16rows x 4xfloat4 (all in-bounds; mterm folded per element)
    for (int q = tid; q < 16 * 16 * 4; q += 256) {
      const int c = q / 64, rem = q % 64, r = rem / 4, f4 = rem % 4;
      const int cg = cc * 16 + c;
      const int gy = hl0 + r, gx0 = wl0 + f4 * 4;
      const float a = s_ab2[cg][0], bb = s_ab2[cg][1];
      const float mh = (float)((gy == 0) + (gy == HL_ - 1));
      float4 v = *reinterpret_cast<const float4*>(pL + (size_t)(b * C_ + cg) * planeSz + gy * WL_ + gx0);
      v.x = fmaf(a, v.x, bb * 0.5f * (mh + (float)((gx0 + 0 == 0) + (gx0 + 0 == WL_ - 1))));
      v.y = fmaf(a, v.y, bb * 0.5f * (mh + (float)((gx0 + 1 == 0) + (gx0 + 1 == WL_ - 1))));
      v.z = fmaf(a, v.z, bb * 0.5f * (mh + (float)((gx0 + 2 == 0) + (gx0 + 2 == WL_ - 1))));
      v.w = fmaf(a, v.w, bb * 0.5f * (mh + (float)((gx0 + 3 == 0) + (gx0 + 3 == WL_ - 1))));
      *reinterpret_cast<float4*>(&s_h[c][r][f4 * 4]) = v;
    }
    __syncthreads();

#pragma unroll 2
    for (int c = 0; c < 16; ++c) {
      const int cg = cc * 16 + c;
      const float vc = s_v[c][pyi + 1][pxi + 4];
      const float vh = s_h[c][pyi][pxi];
      n1 = fmaf(vc, vc, n1);
      const float u0 = s_v[c][pyi][pxi + 3];
      const float u1 = s_v[c][pyi][pxi + 4];
      const float u2 = s_v[c][pyi][pxi + 5];
      const float u3 = s_v[c][pyi + 1][pxi + 3];
      const float u4 = s_v[c][pyi + 1][pxi + 5];
      const float u5 = s_v[c][pyi + 2][pxi + 3];
      const float u6 = s_v[c][pyi + 2][pxi + 4];
      const float u7 = s_v[c][pyi + 2][pxi + 5];
      dot[0] = fmaf(vc, u0, dot[0]); n2[0] = fmaf(u0, u0, n2[0]);
      dot[1] = fmaf(vc, u1, dot[1]); n2[1] = fmaf(u1, u1, n2[1]);
      dot[2] = fmaf(vc, u2, dot[2]); n2[2] = fmaf(u2, u2, n2[2]);
      dot[3] = fmaf(vc, u3, dot[3]); n2[3] = fmaf(u3, u3, n2[3]);
      dot[4] = fmaf(vc, u4, dot[4]); n2[4] = fmaf(u4, u4, n2[4]);
      dot[5] = fmaf(vc, u5, dot[5]); n2[5] = fmaf(u5, u5, n2[5]);
      dot[6] = fmaf(vc, u6, dot[6]); n2[6] = fmaf(u6, u6, n2[6]);
      dot[7] = fmaf(vc, u7, dot[7]); n2[7] = fmaf(u7, u7, n2[7]);
      const float4 mw0 = *reinterpret_cast<const float4*>(&s_mw[cg][0]);
      const float4 mw1 = *reinterpret_cast<const float4*>(&s_mw[cg][4]);
      const float4 hw0 = *reinterpret_cast<const float4*>(&s_hw[cg][0]);
      const float4 hw1 = *reinterpret_cast<const float4*>(&s_hw[cg][4]);
      z[0] = fmaf(mw0.x, vc, fmaf(hw0.x, vh, z[0]));
      z[1] = fmaf(mw0.y, vc, fmaf(hw0.y, vh, z[1]));
      z[2] = fmaf(mw0.z, vc, fmaf(hw0.z, vh, z[2]));
      z[3] = fmaf(mw0.w, vc, fmaf(hw0.w, vh, z[3]));
      z[4] = fmaf(mw1.x, vc, fmaf(hw1.x, vh, z[4]));
      z[5] = fmaf(mw1.y, vc, fmaf(hw1.y, vh, z[5]));
      z[6] = fmaf(mw1.z, vc, fmaf(hw1.z, vh, z[6]));
      z[7] = fmaf(mw1.w, vc, fmaf(hw1.w, vh, z[7]));
    }
  }

  const float n1c = fmaxf(sqrtf(n1), 1e-8f);
  float df[8];
#pragma unroll
  for (int k = 0; k < 8; ++k)
    df[k] = dot[k] / (n1c * fmaxf(sqrtf(n2[k]), 1e-8f));

  float off[8];
#pragma unroll
  for (int o = 0; o < 8; ++o) {
    float t1 = s_bias[1][o];
#pragma unroll
    for (int j = 0; j < 8; ++j) t1 = fmaf(s_dir[o][j], df[j], t1);
    const float zz = z[o] + s_bias[0][o];
    off[o] = t1 / (1.f + expf(-zz));
  }

#pragma unroll
  for (int g = 0; g < GRP; ++g) {
    const float ix = fminf(fmaxf(2.f * wl + 0.5f + off[g], 0.f), (float)(W_ - 1));
    const float iy = fminf(fmaxf(2.f * hl + 0.5f + off[GRP + g], 0.f), (float)(H_ - 1));
    grid[(b * GRP + g) * (HL_ * WL_) + hl * WL_ + wl] = make_float2(ix, iy);
  }
}

// ---------------- Kernel 4: bilinear grid sample (border) ----------------
__global__ __launch_bounds__(256) void k4_sample(const float* __restrict__ x,
                                                 const float2* __restrict__ grid,
                                                 float* __restrict__ out) {
  const int idx = blockIdx.x * 256 + threadIdx.x;
  const int wl = idx & (WL_ - 1);
  const int hl = (idx >> 7) & (HL_ - 1);
  const int bc = idx >> 14;
  const int c = bc & 63;
  const int b = bc >> 6;
  const int g = c >> 4;
  const float2 G = grid[(b * GRP + g) * (HL_ * WL_) + hl * WL_ + wl];
  const float ix = G.x, iy = G.y;
  const float x0f = floorf(ix), y0f = floorf(iy);
  const float wx = ix - x0f, wy = iy - y0f;
  const int x0 = (int)x0f, y0 = (int)y0f;
  const int x1 = min(x0 + 1, W_ - 1), y1 = min(y0 + 1, H_ - 1);
  const float* plane = x + (size_t)bc * (H_ * W_);
  const float v00 = plane[y0 * W_ + x0];
  const float v01 = plane[y0 * W_ + x1];
  const float v10 = plane[y1 * W_ + x0];
  const float v11 = plane[y1 * W_ + x1];
  out[idx] = v00 * (1.f - wx) * (1.f - wy) + v01 * wx * (1.f - wy)
           + v10 * (1.f - wx) * wy + v11 * wx * wy;
}

extern "C" void kernel_launch(void* const* d_in, const int* in_sizes, int n_in,
                              void* d_out, int out_size, void* d_ws, size_t ws_size,
                              hipStream_t stream) {
  const float* x = (const float*)d_in[0];
  const float* gn_gamma = (const float*)d_in[1];
  const float* gn_beta = (const float*)d_in[2];
  const float* hp_weight = (const float*)d_in[3];
  const float* dir_w = (const float*)d_in[4];
  const float* dir_b = (const float*)d_in[5];
  const float* mag_w = (const float*)d_in[6];
  const float* mag_b = (const float*)d_in[7];
  const float* hfg_w = (const float*)d_in[8];
  const float* hfg_b = (const float*)d_in[9];
  float* out = (float*)d_out;

  // ws layout (floats)
  float* ws = (float*)d_ws;
  float* partials = ws;                                  // 8192
  float* ab = ws + 8192;                                 // 1024
  float* px = ws + 16384;                                // 2,097,152
  float* pL = px + (size_t)B_ * C_ * HL_ * WL_;          // 2,097,152
  float2* grid = (float2*)(pL + (size_t)B_ * C_ * HL_ * WL_);  // 1,048,576 floats

  k2_fused<<<B_ * C_ * 8, 256, 0, stream>>>(x, hp_weight, px, pL, partials);
  k1_finish<<<1, 512, 0, stream>>>(partials, gn_gamma, gn_beta, ab);
  k3_offset<<<B_ * (HL_ / TS) * (WL_ / TS), 256, 0, stream>>>(px, pL, ab, dir_w, dir_b,
                                                              mag_w, mag_b, hfg_w, hfg_b, grid);
  k4_sample<<<(B_ * C_ * HL_ * WL_) / 256, 256, 0, stream>>>(x, grid, out);
}

// Round 7
// 104.469 us; speedup vs baseline: 2.6843x; 1.0692x over previous
//
#include <hip/hip_runtime.h>
#include <hip/hip_bf16.h>
#include <math.h>

// Problem constants
#define B_ 8
#define C_ 64
#define H_ 256
#define W_ 256
#define HL_ 128
#define WL_ 128
#define GN_G 8
#define CPG 8
#define GRP 4
#define OC_ 8
#define GROUP_ELEMS (CPG * H_ * W_)   // 524288

#define TILE_H 16       // low-res rows per k2 block
#define XROWS 34        // hi-res rows staged (2*16 + 2 halo)
#define LDSW 264        // LDS row stride in floats (16B-aligned stores at col 4)

// ---------------- Kernel 2': fused GN-partials + pool(x) + pool(L(x)) ----------------
// grid: (b,c) * 8 row-tiles = 4096 blocks, 256 threads
__global__ __launch_bounds__(256) void k2_fused(const float* __restrict__ x,
                                                const float* __restrict__ hpw,
                                                float* __restrict__ px,
                                                float* __restrict__ pL,
                                                float* __restrict__ partials) {
  __shared__ float tile[XROWS * LDSW];   // ~35.9 KB
  __shared__ float rs[4], rs2[4];
  const int t = threadIdx.x;
  const int blk = blockIdx.x;
  const int tileIdx = blk & 7;
  const int bc = blk >> 3;               // b*64+c
  const int c = bc & 63;
  const int hl0 = tileIdx * TILE_H;
  const float* plane = x + (size_t)bc * (H_ * W_);
  const int y0 = 2 * hl0 - 1;

  // zero the two sentinel columns (col 3 <-> x=-1, col 260 <-> x=256)
  if (t < XROWS * 2) {
    const int r = t >> 1;
    tile[r * LDSW + ((t & 1) ? 260 : 3)] = 0.f;
  }

  // stage x rows [y0, y0+33] as float4, accumulate GN partial sums on owned rows
  float s = 0.f, s2 = 0.f;
  for (int i = 0; i < 9; ++i) {
    const int q = t + i * 256;
    if (q >= XROWS * 64) break;
    const int r = q >> 6;
    const int c4 = (q & 63) << 2;
    const int y = y0 + r;
    float4 v = make_float4(0.f, 0.f, 0.f, 0.f);
    if ((unsigned)y < (unsigned)H_)
      v = *reinterpret_cast<const float4*>(plane + y * W_ + c4);
    *reinterpret_cast<float4*>(&tile[r * LDSW + 4 + c4]) = v;
    if (r >= 1 && r <= 32) {   // owned rows: exactly hi-res rows 2*hl0 .. 2*hl0+31
      s  += v.x + v.y + v.z + v.w;
      s2 += v.x * v.x + v.y * v.y + v.z * v.z + v.w * v.w;
    }
  }
#pragma unroll
  for (int off = 32; off > 0; off >>= 1) {
    s  += __shfl_down(s, off, 64);
    s2 += __shfl_down(s2, off, 64);
  }
  if ((t & 63) == 0) { rs[t >> 6] = s; rs2[t >> 6] = s2; }
  __syncthreads();
  if (t == 0) {
    partials[blk * 2 + 0] = rs[0] + rs[1] + rs[2] + rs[3];
    partials[blk * 2 + 1] = rs2[0] + rs2[1] + rs2[2] + rs2[3];
  }

  // depthwise weights (wave-uniform: c uniform per block)
  float w[9];
#pragma unroll
  for (int i = 0; i < 9; ++i) w[i] = hpw[c * 9 + i];

  // compute 8 vertical outputs per thread from LDS with rolling 4x4 window
  const int wl = t & 127;
  const int hs = (t >> 7) * 8;           // 0 or 8
  const int colb = 3 + 2 * wl;
  const int rbase = 2 * hs;
  float win[4][4];
#pragma unroll
  for (int j = 0; j < 4; ++j)
#pragma unroll
    for (int d = 0; d < 4; ++d)
      win[j][d] = tile[(rbase + j) * LDSW + colb + d];

  int outIdx = (bc * HL_ + (hl0 + hs)) * WL_ + wl;
#pragma unroll
  for (int i = 0; i < 8; ++i) {
    float pr[4][3];
#pragma unroll
    for (int j = 0; j < 4; ++j)
#pragma unroll
      for (int d = 0; d < 3; ++d) pr[j][d] = win[j][d] + win[j][d + 1];
    float hfsum = 0.f;
    float q11 = 0.f;
#pragma unroll
    for (int j = 0; j < 3; ++j)
#pragma unroll
      for (int d = 0; d < 3; ++d) {
        const float qq = pr[j][d] + pr[j + 1][d];
        hfsum = fmaf(w[j * 3 + d], qq, hfsum);
        if (j == 1 && d == 1) q11 = qq;
      }
    px[outIdx] = 0.25f * q11;
    pL[outIdx] = 0.25f * hfsum;
    outIdx += WL_;
    if (i < 7) {
      const int rn = rbase + 2 * i + 4;
#pragma unroll
      for (int d = 0; d < 4; ++d) {
        win[0][d] = win[2][d];
        win[1][d] = win[3][d];
        win[2][d] = tile[rn * LDSW + colb + d];
        win[3][d] = tile[(rn + 1) * LDSW + colb + d];
      }
    }
  }
}

// ---------------- Kernel 1b: finalize per-(b,c) affine ----------------
__global__ __launch_bounds__(512) void k1_finish(const float* __restrict__ partials,
                                                 const float* __restrict__ gamma,
                                                 const float* __restrict__ beta,
                                                 float* __restrict__ ab) {
  const int t = threadIdx.x;
  const int b = t >> 6, c = t & 63, g = c >> 3;
  float S = 0.f, S2 = 0.f;
  for (int c2 = g * CPG; c2 < g * CPG + CPG; ++c2)
#pragma unroll
    for (int p = 0; p < 8; ++p) {
      const int blk = (b * 64 + c2) * 8 + p;
      S  += partials[blk * 2 + 0];
      S2 += partials[blk * 2 + 1];
    }
  const float N = (float)GROUP_ELEMS;
  const float mean = S / N;
  const float var = fmaxf(S2 / N - mean * mean, 0.f);
  const float a = rsqrtf(var + 1e-5f) * gamma[c];
  ab[t * 2 + 0] = a;
  ab[t * 2 + 1] = beta[c] - mean * a;
}

// ---------------- Kernel 3 (v5): double-buffered LDS tile, vh from global ----------------
// One block = 16x16 pixel tile of one batch; 4 chunks of 16 channels.
// s_v double-buffered: stage(cc+1) overlaps compute(cc). hfl read straight from
// global (zero reuse -> no staging). grid: 512 blocks x 256 threads.
#define TS 16
__global__ __launch_bounds__(256) void k3_offset(const float* __restrict__ px,
                                                 const float* __restrict__ pL,
                                                 const float* __restrict__ ab,
                                                 const float* __restrict__ dir_w,
                                                 const float* __restrict__ dir_b,
                                                 const float* __restrict__ mag_w,
                                                 const float* __restrict__ mag_b,
                                                 const float* __restrict__ hfg_w,
                                                 const float* __restrict__ hfg_b,
                                                 float2* __restrict__ grid) {
  __shared__ float s_v[2][16][18][24];  // 55.3 KB: affine xl tile + halo, dbuf
  __shared__ float s_mw[C_][OC_];       // transposed mag_w
  __shared__ float s_hw[C_][OC_];       // transposed hfg_w
  __shared__ float s_dir[OC_][8];
  __shared__ float s_ab2[C_][2];
  __shared__ float s_bias[2][OC_];

  const int tid = threadIdx.x;
  const int bx = blockIdx.x;
  const int tx = bx & 7, ty = (bx >> 3) & 7, b = bx >> 6;
  const int hl0 = ty * TS, wl0 = tx * TS;
  const size_t planeSz = (size_t)HL_ * WL_;

  for (int i = tid; i < OC_ * C_; i += 256) {
    const int o = i >> 6, c = i & 63;
    s_mw[c][o] = mag_w[i];
    s_hw[c][o] = hfg_w[i];
  }
  if (tid < 64) s_dir[tid >> 3][tid & 7] = dir_w[tid];
  if (tid < 128) s_ab2[tid >> 1][tid & 1] = ab[b * 128 + tid];
  if (tid < OC_) { s_bias[0][tid] = mag_b[tid] + hfg_b[tid]; s_bias[1][tid] = dir_b[tid]; }
  __syncthreads();   // s_ab2 ready (stage reads it)

  // stage chunk cc (16 channels) into s_v[sel]
  auto stage = [&](int cc, int sel) {
    for (int q = tid; q < 16 * 18 * 6; q += 256) {
      const int c = q / 108, rem = q % 108, r = rem / 6, f4 = rem % 6;
      const int cg = cc * 16 + c;
      const int gy = hl0 - 1 + r;
      const int gx0 = wl0 - 4 + f4 * 4;
      const float a = s_ab2[cg][0], bb = s_ab2[cg][1];
      const float* pp = px + (size_t)(b * C_ + cg) * planeSz + gy * WL_ + gx0;
      float4 v = make_float4(0.f, 0.f, 0.f, 0.f);
      if ((unsigned)gy < (unsigned)HL_) {
        if (gx0 >= 0 && gx0 + 3 < WL_) {
          v = *reinterpret_cast<const float4*>(pp);
          v.x = fmaf(a, v.x, bb); v.y = fmaf(a, v.y, bb);
          v.z = fmaf(a, v.z, bb); v.w = fmaf(a, v.w, bb);
        } else {
          if ((unsigned)(gx0 + 0) < (unsigned)WL_) v.x = fmaf(a, pp[0], bb);
          if ((unsigned)(gx0 + 1) < (unsigned)WL_) v.y = fmaf(a, pp[1], bb);
          if ((unsigned)(gx0 + 2) < (unsigned)WL_) v.z = fmaf(a, pp[2], bb);
          if ((unsigned)(gx0 + 3) < (unsigned)WL_) v.w = fmaf(a, pp[3], bb);
        }
      }
      *reinterpret_cast<float4*>(&s_v[sel][c][r][f4 * 4]) = v;
    }
  };

  const int pxi = tid & 15, pyi = tid >> 4;
  const int hl = hl0 + pyi, wl = wl0 + pxi;
  const float mterm = 0.5f * ((hl == 0) + (hl == HL_ - 1) + (wl == 0) + (wl == WL_ - 1));

  float dot[8], n2[8], z[8], n1 = 0.f;
#pragma unroll
  for (int k = 0; k < 8; ++k) { dot[k] = 0.f; n2[k] = 0.f; z[k] = 0.f; }

  stage(0, 0);
  __syncthreads();

  for (int cc = 0; cc < 4; ++cc) {
    if (cc < 3) stage(cc + 1, (cc + 1) & 1);     // overlaps compute below
    const int sel = cc & 1;
    // prefetch all 16 hfl values (coalesced, independent loads)
    float lh[16];
    const size_t pbase = (size_t)(b * C_ + cc * 16) * planeSz + hl * WL_ + wl;
#pragma unroll
    for (int c = 0; c < 16; ++c) lh[c] = pL[pbase + c * planeSz];
#pragma unroll
    for (int c = 0; c < 16; ++c) {
      const int cg = cc * 16 + c;
      const float a = s_ab2[cg][0], bb = s_ab2[cg][1];
      const float vc = s_v[sel][c][pyi + 1][pxi + 4];
      const float vh = fmaf(a, lh[c], bb * mterm);
      n1 = fmaf(vc, vc, n1);
      const float u0 = s_v[sel][c][pyi][pxi + 3];
      const float u1 = s_v[sel][c][pyi][pxi + 4];
      const float u2 = s_v[sel][c][pyi][pxi + 5];
      const float u3 = s_v[sel][c][pyi + 1][pxi + 3];
      const float u4 = s_v[sel][c][pyi + 1][pxi + 5];
      const float u5 = s_v[sel][c][pyi + 2][pxi + 3];
      const float u6 = s_v[sel][c][pyi + 2][pxi + 4];
      const float u7 = s_v[sel][c][pyi + 2][pxi + 5];
      dot[0] = fmaf(vc, u0, dot[0]); n2[0] = fmaf(u0, u0, n2[0]);
      dot[1] = fmaf(vc, u1, dot[1]); n2[1] = fmaf(u1, u1, n2[1]);
      dot[2] = fmaf(vc, u2, dot[2]); n2[2] = fmaf(u2, u2, n2[2]);
      dot[3] = fmaf(vc, u3, dot[3]); n2[3] = fmaf(u3, u3, n2[3]);
      dot[4] = fmaf(vc, u4, dot[4]); n2[4] = fmaf(u4, u4, n2[4]);
      dot[5] = fmaf(vc, u5, dot[5]); n2[5] = fmaf(u5, u5, n2[5]);
      dot[6] = fmaf(vc, u6, dot[6]); n2[6] = fmaf(u6, u6, n2[6]);
      dot[7] = fmaf(vc, u7, dot[7]); n2[7] = fmaf(u7, u7, n2[7]);
      const float4 mw0 = *reinterpret_cast<const float4*>(&s_mw[cg][0]);
      const float4 mw1 = *reinterpret_cast<const float4*>(&s_mw[cg][4]);
      const float4 hw0 = *reinterpret_cast<const float4*>(&s_hw[cg][0]);
      const float4 hw1 = *reinterpret_cast<const float4*>(&s_hw[cg][4]);
      z[0] = fmaf(mw0.x, vc, fmaf(hw0.x, vh, z[0]));
      z[1] = fmaf(mw0.y, vc, fmaf(hw0.y, vh, z[1]));
      z[2] = fmaf(mw0.z, vc, fmaf(hw0.z, vh, z[2]));
      z[3] = fmaf(mw0.w, vc, fmaf(hw0.w, vh, z[3]));
      z[4] = fmaf(mw1.x, vc, fmaf(hw1.x, vh, z[4]));
      z[5] = fmaf(mw1.y, vc, fmaf(hw1.y, vh, z[5]));
      z[6] = fmaf(mw1.z, vc, fmaf(hw1.z, vh, z[6]));
      z[7] = fmaf(mw1.w, vc, fmaf(hw1.w, vh, z[7]));
    }
    __syncthreads();   // buf[(cc+1)&1] staged; buf[cc&1] free for next stage
  }

  const float n1c = fmaxf(sqrtf(n1), 1e-8f);
  float df[8];
#pragma unroll
  for (int k = 0; k < 8; ++k)
    df[k] = dot[k] / (n1c * fmaxf(sqrtf(n2[k]), 1e-8f));

  float off[8];
#pragma unroll
  for (int o = 0; o < 8; ++o) {
    float t1 = s_bias[1][o];
#pragma unroll
    for (int j = 0; j < 8; ++j) t1 = fmaf(s_dir[o][j], df[j], t1);
    const float zz = z[o] + s_bias[0][o];
    off[o] = t1 / (1.f + expf(-zz));
  }

#pragma unroll
  for (int g = 0; g < GRP; ++g) {
    const float ix = fminf(fmaxf(2.f * wl + 0.5f + off[g], 0.f), (float)(W_ - 1));
    const float iy = fminf(fmaxf(2.f * hl + 0.5f + off[GRP + g], 0.f), (float)(H_ - 1));
    grid[(b * GRP + g) * (HL_ * WL_) + hl * WL_ + wl] = make_float2(ix, iy);
  }
}

// ---------------- Kernel 4 (v2): bilinear grid sample, 4 channels/thread ----------------
// thread <-> (b, g, qc, hl, wl); handles channels c = g*16 + qc*4 .. +3.
__global__ __launch_bounds__(256) void k4_sample(const float* __restrict__ x,
                                                 const float2* __restrict__ grid,
                                                 float* __restrict__ out) {
  const int idx = blockIdx.x * 256 + threadIdx.x;   // B*GRP*4*HL*WL = 2,097,152
  const int wl = idx & (WL_ - 1);
  const int hl = (idx >> 7) & (HL_ - 1);
  const int qc = (idx >> 14) & 3;
  const int g = (idx >> 16) & 3;
  const int b = idx >> 18;
  const float2 G = grid[(b * GRP + g) * (HL_ * WL_) + hl * WL_ + wl];
  const float ix = G.x, iy = G.y;
  const float x0f = floorf(ix), y0f = floorf(iy);
  const float wx = ix - x0f, wy = iy - y0f;
  const int x0 = (int)x0f, y0 = (int)y0f;
  const int x1 = min(x0 + 1, W_ - 1), y1 = min(y0 + 1, H_ - 1);
  const float w00 = (1.f - wx) * (1.f - wy), w01 = wx * (1.f - wy);
  const float w10 = (1.f - wx) * wy,        w11 = wx * wy;
  const int c0 = g * 16 + qc * 4;
  const float* plane = x + (size_t)(b * C_ + c0) * (H_ * W_);
  float* po = out + (size_t)(b * C_ + c0) * (HL_ * WL_) + hl * WL_ + wl;
#pragma unroll
  for (int j = 0; j < 4; ++j) {
    const float v00 = plane[y0 * W_ + x0];
    const float v01 = plane[y0 * W_ + x1];
    const float v10 = plane[y1 * W_ + x0];
    const float v11 = plane[y1 * W_ + x1];
    *po = fmaf(v00, w00, fmaf(v01, w01, fmaf(v10, w10, v11 * w11)));
    plane += H_ * W_;
    po += HL_ * WL_;
  }
}

extern "C" void kernel_launch(void* const* d_in, const int* in_sizes, int n_in,
                              void* d_out, int out_size, void* d_ws, size_t ws_size,
                              hipStream_t stream) {
  const float* x = (const float*)d_in[0];
  const float* gn_gamma = (const float*)d_in[1];
  const float* gn_beta = (const float*)d_in[2];
  const float* hp_weight = (const float*)d_in[3];
  const float* dir_w = (const float*)d_in[4];
  const float* dir_b = (const float*)d_in[5];
  const float* mag_w = (const float*)d_in[6];
  const float* mag_b = (const float*)d_in[7];
  const float* hfg_w = (const float*)d_in[8];
  const float* hfg_b = (const float*)d_in[9];
  float* out = (float*)d_out;

  // ws layout (floats)
  float* ws = (float*)d_ws;
  float* partials = ws;                                  // 8192
  float* ab = ws + 8192;                                 // 1024
  float* px = ws + 16384;                                // 2,097,152
  float* pL = px + (size_t)B_ * C_ * HL_ * WL_;          // 2,097,152
  float2* grid = (float2*)(pL + (size_t)B_ * C_ * HL_ * WL_);  // 1,048,576 floats

  k2_fused<<<B_ * C_ * 8, 256, 0, stream>>>(x, hp_weight, px, pL, partials);
  k1_finish<<<1, 512, 0, stream>>>(partials, gn_gamma, gn_beta, ab);
  k3_offset<<<B_ * (HL_ / TS) * (WL_ / TS), 256, 0, stream>>>(px, pL, ab, dir_w, dir_b,
                                                              mag_w, mag_b, hfg_w, hfg_b, grid);
  k4_sample<<<(B_ * GRP * 4 * HL_ * WL_) / 256, 256, 0, stream>>>(x, grid, out);
}